// Round 7
// baseline (103.961 us; speedup 1.0000x reference)
//
#include <hip/hip_runtime.h>

// Laplacian3D: LDS plane-ring (10 slots = 160 KiB) + per-thread register z-ring,
// z-loop FULLY UNROLLED so the 9-deep ring has static indices (register renaming,
// no v_mov shift — R6's mistake). Per step: 1 ring-fill + 6 y-tap + 2 w-tap
// ds_reads (9 total), ~90 VALU, one barrier. Prefetch distance 1 via
// global_load_lds; barrier's vmcnt(0) drain is hidden under the compute phase.

#define NSLOT 10
#define PLANE 4096   // 64*64 floats = 16 KB
#define CHUNK 32

typedef float fx4 __attribute__((ext_vector_type(4)));

#define GLD(gsrc, ldst) __builtin_amdgcn_global_load_lds(                      \
    (const __attribute__((address_space(1))) unsigned int*)(gsrc),             \
    (__attribute__((address_space(3))) unsigned int*)(ldst), 16, 0, 0)

#define F4E(v, j) ((j) == 0 ? (v).x : (j) == 1 ? (v).y : (j) == 2 ? (v).z : (v).w)

__global__ __launch_bounds__(1024, 4) void lap3d_uring(
    const float* __restrict__ x, const float* __restrict__ p,
    float* __restrict__ out)
{
    __shared__ __align__(16) float lds[NSLOT][PLANE];   // 163840 B = 160 KiB

    const int tid   = threadIdx.x;
    const int bc    = blockIdx.x >> 1;        // b*64 + c
    const int chunk = blockIdx.x & 1;
    const int z0    = chunk * CHUNK;
    const int s0    = z0 % NSLOT;             // slot of plane z0 (0 or 2)
    const int c     = bc & 63;

    const float* vol  = x   + (size_t)bc * (64 * PLANE);
    float*       ovol = out + (size_t)bc * (64 * PLANE);

    const int y     = tid >> 4;
    const int w0    = (tid & 15) << 2;
    const int foff  = tid << 2;               // y*64 + w0
    const int wbase = (tid >> 6) << 8;        // wave's float base in a plane

    const float k1  = 0.25f / (1.0f + __expf(-p[c]));
    const float k2  = 0.25f / (1.0f + __expf(-p[64 + c]));
    const float k4  = 0.25f / (1.0f + __expf(-p[128 + c]));
    const float km6 = -6.0f * (k1 + k2 + k4);

    // y-tap clamped offsets + masks (z-independent)
    const int dys[6] = {-4, -2, -1, 1, 2, 4};
    int yoff[6]; float ym[6];
#pragma unroll
    for (int k = 0; k < 6; ++k) {
        const int yy = y + dys[k];
        const bool v = (unsigned)yy < 64u;
        yoff[k] = (v ? yy : y) * 64 + w0;
        ym[k]   = v ? 1.0f : 0.0f;
    }
    // w-tap clamped offsets + masks (quad-aligned)
    const bool wmv = (w0 >= 4), wpv = (w0 <= 56);
    const int   wmoff = wmv ? foff - 4 : foff;
    const int   wpoff = wpv ? foff + 4 : foff;
    const float wmm = wmv ? 1.0f : 0.0f, wpm = wpv ? 1.0f : 0.0f;

    // prologue: planes z0-4 .. z0+4 into slots q%10
#pragma unroll
    for (int i = 0; i < 9; ++i) {
        const int q = z0 - 4 + i;
        if (q >= 0 && q < 64)                 // uniform
            GLD(vol + (size_t)q * PLANE + foff, &lds[q % NSLOT][wbase]);
    }
    __syncthreads();

    const float4 zero = make_float4(0.f, 0.f, 0.f, 0.f);

    // register z-ring: plane q lives at ring[(q - z0 + 4) % 9].
    // init ring[0..7] = planes z0-4 .. z0+3; ring[8] filled in step 0.
    float4 ring[9];
#pragma unroll
    for (int i = 0; i < 8; ++i) {
        const int q = z0 - 4 + i;
        ring[i] = (q >= 0) ? *(const float4*)(&lds[q % NSLOT][foff]) : zero;
    }
    ring[8] = zero;

#pragma unroll
    for (int iz = 0; iz < CHUNK; ++iz) {       // fully unrolled: iz is literal
        const int z = z0 + iz;

        // prefetch plane z+5 into slot (z0+iz+5)%10 (scalar arithmetic)
        {
            int sl = s0 + (iz + 5) % NSLOT; if (sl >= NSLOT) sl -= NSLOT;
            if (z + 5 < 64 && iz < CHUNK - 1)  // uniform
                GLD(vol + (size_t)(z + 5) * PLANE + foff, &lds[sl][wbase]);
        }

        // ring fill: plane z+4 -> ring[(iz+8)%9] (static index)
        {
            int sl = s0 + (iz + 4) % NSLOT; if (sl >= NSLOT) sl -= NSLOT;
            ring[(iz + 8) % 9] = (z + 4 < 64)
                ? *(const float4*)(&lds[sl][foff]) : zero;
        }

        int slc = s0 + iz % NSLOT; if (slc >= NSLOT) slc -= NSLOT;
        const float* plz = lds[slc];

        // z taps from registers (static ring indices)
        const float4 ctr = ring[(iz + 4) % 9];
        const float4 zm1 = ring[(iz + 3) % 9], zp1 = ring[(iz + 5) % 9];
        const float4 zm2 = ring[(iz + 2) % 9], zp2 = ring[(iz + 6) % 9];
        const float4 zm4 = ring[(iz + 0) % 9], zp4 = ring[(iz + 8) % 9];

        // w-window + y-taps from the center plane in LDS
        const float4 wm = *(const float4*)(plz + wmoff);
        const float4 wp = *(const float4*)(plz + wpoff);
        const float4 ym4t = *(const float4*)(plz + yoff[0]);
        const float4 ym2t = *(const float4*)(plz + yoff[1]);
        const float4 ym1t = *(const float4*)(plz + yoff[2]);
        const float4 yp1t = *(const float4*)(plz + yoff[3]);
        const float4 yp2t = *(const float4*)(plz + yoff[4]);
        const float4 yp4t = *(const float4*)(plz + yoff[5]);

        const float win[12] = {wm.x * wmm, wm.y * wmm, wm.z * wmm, wm.w * wmm,
                               ctr.x, ctr.y, ctr.z, ctr.w,
                               wp.x * wpm, wp.y * wpm, wp.z * wpm, wp.w * wpm};

        fx4 o;
#pragma unroll
        for (int j = 0; j < 4; ++j) {
            const float s1 = F4E(zm1, j) + F4E(zp1, j) + win[3 + j] + win[5 + j]
                           + ym[2] * F4E(ym1t, j) + ym[3] * F4E(yp1t, j);
            const float s2 = F4E(zm2, j) + F4E(zp2, j) + win[2 + j] + win[6 + j]
                           + ym[1] * F4E(ym2t, j) + ym[4] * F4E(yp2t, j);
            const float s4 = F4E(zm4, j) + F4E(zp4, j) + win[j] + win[8 + j]
                           + ym[0] * F4E(ym4t, j) + ym[5] * F4E(yp4t, j);
            o[j] = km6 * win[4 + j] + k1 * s1 + k2 * s2 + k4 * s4;
        }
        __builtin_nontemporal_store(o, (fx4*)(ovol + (size_t)z * PLANE + foff));

        __syncthreads();   // drains prefetch (hidden under compute); frees
                           // slot (z-4) for the next step's prefetch
    }
}

extern "C" void kernel_launch(void* const* d_in, const int* in_sizes, int n_in,
                              void* d_out, int out_size, void* d_ws, size_t ws_size,
                              hipStream_t stream) {
    const float* x = (const float*)d_in[0];
    const float* p = (const float*)d_in[1];
    float* out = (float*)d_out;
    lap3d_uring<<<256, 1024, 0, stream>>>(x, p, out);
}

// Round 8
// 80.304 us; speedup vs baseline: 1.2946x; 1.2946x over previous
//
#include <hip/hip_runtime.h>

// Laplacian3D: LDS plane-ring (10 slots = 160 KiB) + per-thread register z-ring,
// z-loop fully unrolled (static ring indices = register renaming, no movs).
// R7 spilled to scratch: __launch_bounds__(1024,4) clamped VGPRs to 64
// (2nd arg acts as min-BLOCKS/CU -> 32 waves -> 64-reg cap; WRITE_SIZE showed
// +77 MB of spill traffic). Fix: (1024,1) -> 16 waves/CU -> 128-reg cap.
// LDS (160 KiB) limits us to 1 block/CU regardless, so occupancy is unchanged.
// Per step: 1 ring-fill + 6 y-tap + 2 w-tap ds_reads (9 total), one barrier,
// prefetch distance 1 via global_load_lds (latency hidden under compute).

#define NSLOT 10
#define PLANE 4096   // 64*64 floats = 16 KB
#define CHUNK 32

typedef float fx4 __attribute__((ext_vector_type(4)));

#define GLD(gsrc, ldst) __builtin_amdgcn_global_load_lds(                      \
    (const __attribute__((address_space(1))) unsigned int*)(gsrc),             \
    (__attribute__((address_space(3))) unsigned int*)(ldst), 16, 0, 0)

#define F4E(v, j) ((j) == 0 ? (v).x : (j) == 1 ? (v).y : (j) == 2 ? (v).z : (v).w)

__global__ __launch_bounds__(1024, 1) void lap3d_uring2(
    const float* __restrict__ x, const float* __restrict__ p,
    float* __restrict__ out)
{
    __shared__ __align__(16) float lds[NSLOT][PLANE];   // 163840 B = 160 KiB

    const int tid   = threadIdx.x;
    const int bc    = blockIdx.x >> 1;        // b*64 + c
    const int chunk = blockIdx.x & 1;
    const int z0    = chunk * CHUNK;
    const int s0    = z0 % NSLOT;             // slot of plane z0 (0 or 2)
    const int c     = bc & 63;

    const float* vol  = x   + (size_t)bc * (64 * PLANE);
    float*       ovol = out + (size_t)bc * (64 * PLANE);

    const int y     = tid >> 4;
    const int w0    = (tid & 15) << 2;
    const int foff  = tid << 2;               // y*64 + w0
    const int wbase = (tid >> 6) << 8;        // wave's float base in a plane

    const float k1  = 0.25f / (1.0f + __expf(-p[c]));
    const float k2  = 0.25f / (1.0f + __expf(-p[64 + c]));
    const float k4  = 0.25f / (1.0f + __expf(-p[128 + c]));
    const float km6 = -6.0f * (k1 + k2 + k4);

    // y-tap clamped offsets + masks (z-independent)
    const int dys[6] = {-4, -2, -1, 1, 2, 4};
    int yoff[6]; float ym[6];
#pragma unroll
    for (int k = 0; k < 6; ++k) {
        const int yy = y + dys[k];
        const bool v = (unsigned)yy < 64u;
        yoff[k] = (v ? yy : y) * 64 + w0;
        ym[k]   = v ? 1.0f : 0.0f;
    }
    // w-tap clamped offsets + masks (quad-aligned)
    const bool wmv = (w0 >= 4), wpv = (w0 <= 56);
    const int   wmoff = wmv ? foff - 4 : foff;
    const int   wpoff = wpv ? foff + 4 : foff;
    const float wmm = wmv ? 1.0f : 0.0f, wpm = wpv ? 1.0f : 0.0f;

    // prologue: planes z0-4 .. z0+4 into slots q%10
#pragma unroll
    for (int i = 0; i < 9; ++i) {
        const int q = z0 - 4 + i;
        if (q >= 0 && q < 64)                 // uniform
            GLD(vol + (size_t)q * PLANE + foff, &lds[q % NSLOT][wbase]);
    }
    __syncthreads();

    const float4 zero = make_float4(0.f, 0.f, 0.f, 0.f);

    // register z-ring: plane q lives at ring[(q - z0 + 4) % 9].
    // init ring[0..7] = planes z0-4 .. z0+3; ring[8] filled in step 0.
    float4 ring[9];
#pragma unroll
    for (int i = 0; i < 8; ++i) {
        const int q = z0 - 4 + i;
        ring[i] = (q >= 0) ? *(const float4*)(&lds[q % NSLOT][foff]) : zero;
    }
    ring[8] = zero;

#pragma unroll
    for (int iz = 0; iz < CHUNK; ++iz) {       // fully unrolled: iz is literal
        const int z = z0 + iz;

        // prefetch plane z+5 into slot (z0+iz+5)%10 (scalar arithmetic)
        {
            int sl = s0 + (iz + 5) % NSLOT; if (sl >= NSLOT) sl -= NSLOT;
            if (z + 5 < 64 && iz < CHUNK - 1)  // uniform
                GLD(vol + (size_t)(z + 5) * PLANE + foff, &lds[sl][wbase]);
        }

        // ring fill: plane z+4 -> ring[(iz+8)%9] (static index)
        {
            int sl = s0 + (iz + 4) % NSLOT; if (sl >= NSLOT) sl -= NSLOT;
            ring[(iz + 8) % 9] = (z + 4 < 64)
                ? *(const float4*)(&lds[sl][foff]) : zero;
        }

        int slc = s0 + iz % NSLOT; if (slc >= NSLOT) slc -= NSLOT;
        const float* plz = lds[slc];

        // z taps from registers (static ring indices)
        const float4 ctr = ring[(iz + 4) % 9];
        const float4 zm1 = ring[(iz + 3) % 9], zp1 = ring[(iz + 5) % 9];
        const float4 zm2 = ring[(iz + 2) % 9], zp2 = ring[(iz + 6) % 9];
        const float4 zm4 = ring[(iz + 0) % 9], zp4 = ring[(iz + 8) % 9];

        // w-window + y-taps from the center plane in LDS
        const float4 wm = *(const float4*)(plz + wmoff);
        const float4 wp = *(const float4*)(plz + wpoff);
        const float4 ym4t = *(const float4*)(plz + yoff[0]);
        const float4 ym2t = *(const float4*)(plz + yoff[1]);
        const float4 ym1t = *(const float4*)(plz + yoff[2]);
        const float4 yp1t = *(const float4*)(plz + yoff[3]);
        const float4 yp2t = *(const float4*)(plz + yoff[4]);
        const float4 yp4t = *(const float4*)(plz + yoff[5]);

        const float win[12] = {wm.x * wmm, wm.y * wmm, wm.z * wmm, wm.w * wmm,
                               ctr.x, ctr.y, ctr.z, ctr.w,
                               wp.x * wpm, wp.y * wpm, wp.z * wpm, wp.w * wpm};

        fx4 o;
#pragma unroll
        for (int j = 0; j < 4; ++j) {
            const float s1 = F4E(zm1, j) + F4E(zp1, j) + win[3 + j] + win[5 + j]
                           + ym[2] * F4E(ym1t, j) + ym[3] * F4E(yp1t, j);
            const float s2 = F4E(zm2, j) + F4E(zp2, j) + win[2 + j] + win[6 + j]
                           + ym[1] * F4E(ym2t, j) + ym[4] * F4E(yp2t, j);
            const float s4 = F4E(zm4, j) + F4E(zp4, j) + win[j] + win[8 + j]
                           + ym[0] * F4E(ym4t, j) + ym[5] * F4E(yp4t, j);
            o[j] = km6 * win[4 + j] + k1 * s1 + k2 * s2 + k4 * s4;
        }
        __builtin_nontemporal_store(o, (fx4*)(ovol + (size_t)z * PLANE + foff));

        __syncthreads();   // drains prefetch (hidden under compute); frees
                           // slot (z-4) for the next step's prefetch
    }
}

extern "C" void kernel_launch(void* const* d_in, const int* in_sizes, int n_in,
                              void* d_out, int out_size, void* d_ws, size_t ws_size,
                              hipStream_t stream) {
    const float* x = (const float*)d_in[0];
    const float* p = (const float*)d_in[1];
    float* out = (float*)d_out;
    lap3d_uring2<<<256, 1024, 0, stream>>>(x, p, out);
}

// Round 9
// 50.062 us; speedup vs baseline: 2.0766x; 1.6041x over previous
//
#include <hip/hip_runtime.h>

// Laplacian3D: LDS plane-ring (10 slots = 160 KiB) + NAMED-register z-ring.
// R7/R8 lesson (rule #20): float4 ring[9] with (iz+k)%9 indices goes to
// scratch — SROA runs before unrolling, so the array is "dynamically indexed"
// and demoted to local memory (counters: VGPR stuck at 64, +77MB WRITE of
// spill traffic). Fix: 8 individually NAMED float4 vars a0..a7 holding planes
// z-4..z+3, rotated via macro argument permutation (pure SSA renaming, no
// movs, no array). The z+4 tap is a direct LDS read that doubles as the ring
// fill for the next step: 9 ds_reads/step total (1 fill + 6 y + 2 w).
// Period 8 divides CHUNK=32: outer loop 4x, body = 8 hand-rotated steps.

#define NSLOT 10
#define PLANE 4096   // 64*64 floats = 16 KB
#define CHUNK 32

typedef float fx4 __attribute__((ext_vector_type(4)));

#define GLD(gsrc, ldst) __builtin_amdgcn_global_load_lds(                      \
    (const __attribute__((address_space(1))) unsigned int*)(gsrc),             \
    (__attribute__((address_space(3))) unsigned int*)(ldst), 16, 0, 0)

#define F4E(v, j) ((j) == 0 ? (v).x : (j) == 1 ? (v).y : (j) == 2 ? (v).z : (v).w)

// One z-step. A0 holds plane z-4 on entry, plane z+4 on exit (the fill).
// A2=z-2, A3=z-1, A4=z (center), A5=z+1, A6=z+2.  (A1, A7 idle this step.)
#define STEP(IZ, A0, A1, A2, A3, A4, A5, A6, A7)                               \
  {                                                                            \
    const int z = z0 + (IZ);                                                   \
    /* prefetch plane z+5 into slot slp (freed: plane z-5, last read z-5) */   \
    if ((z + 5 < 64) && ((IZ) < CHUNK - 1))        /* uniform */               \
        GLD(gp, &lds[slp][wbase]);                                             \
    const float4 zm4 = A0;                                                     \
    A0 = (z + 4 < 64) ? *(const float4*)(&lds[slf][foff]) : zero;              \
    const float4 zp4 = A0;                                                     \
    const float4 zm2 = A2, zm1 = A3, ctr = A4, zp1 = A5, zp2 = A6;             \
    const float* plz = &lds[slc][0];                                           \
    const float4 wm = *(const float4*)(plz + wmoff);                           \
    const float4 wp = *(const float4*)(plz + wpoff);                           \
    const float4 ym4t = *(const float4*)(plz + yoff[0]);                       \
    const float4 ym2t = *(const float4*)(plz + yoff[1]);                       \
    const float4 ym1t = *(const float4*)(plz + yoff[2]);                       \
    const float4 yp1t = *(const float4*)(plz + yoff[3]);                       \
    const float4 yp2t = *(const float4*)(plz + yoff[4]);                       \
    const float4 yp4t = *(const float4*)(plz + yoff[5]);                       \
    const float win[12] = {wm.x * wmm, wm.y * wmm, wm.z * wmm, wm.w * wmm,     \
                           ctr.x, ctr.y, ctr.z, ctr.w,                         \
                           wp.x * wpm, wp.y * wpm, wp.z * wpm, wp.w * wpm};    \
    fx4 o;                                                                     \
    _Pragma("unroll")                                                          \
    for (int j = 0; j < 4; ++j) {                                              \
        const float s1 = F4E(zm1, j) + F4E(zp1, j) + win[3 + j] + win[5 + j]   \
                       + ym[2] * F4E(ym1t, j) + ym[3] * F4E(yp1t, j);          \
        const float s2 = F4E(zm2, j) + F4E(zp2, j) + win[2 + j] + win[6 + j]   \
                       + ym[1] * F4E(ym2t, j) + ym[4] * F4E(yp2t, j);          \
        const float s4 = F4E(zm4, j) + F4E(zp4, j) + win[j] + win[8 + j]       \
                       + ym[0] * F4E(ym4t, j) + ym[5] * F4E(yp4t, j);          \
        o[j] = km6 * win[4 + j] + k1 * s1 + k2 * s2 + k4 * s4;                 \
    }                                                                          \
    __builtin_nontemporal_store(o, (fx4*)op_);                                 \
    __syncthreads();   /* drains prefetch; frees slot of plane z-4 */          \
    slc = (slc + 1 == NSLOT) ? 0 : slc + 1;                                    \
    slf = (slf + 1 == NSLOT) ? 0 : slf + 1;                                    \
    slp = (slp + 1 == NSLOT) ? 0 : slp + 1;                                    \
    gp += PLANE; op_ += PLANE;                                                 \
  }

__global__ __launch_bounds__(1024) void lap3d_nring(
    const float* __restrict__ x, const float* __restrict__ p,
    float* __restrict__ out)
{
    __shared__ __align__(16) float lds[NSLOT][PLANE];   // 163840 B = 160 KiB

    const int tid   = threadIdx.x;
    const int bc    = blockIdx.x >> 1;        // b*64 + c
    const int chunk = blockIdx.x & 1;
    const int z0    = chunk * CHUNK;
    const int c     = bc & 63;

    const float* vol  = x   + (size_t)bc * (64 * PLANE);
    float*       ovol = out + (size_t)bc * (64 * PLANE);

    const int y     = tid >> 4;
    const int w0    = (tid & 15) << 2;
    const int foff  = tid << 2;               // y*64 + w0
    const int wbase = (tid >> 6) << 8;        // wave's float base in a plane

    const float k1  = 0.25f / (1.0f + __expf(-p[c]));
    const float k2  = 0.25f / (1.0f + __expf(-p[64 + c]));
    const float k4  = 0.25f / (1.0f + __expf(-p[128 + c]));
    const float km6 = -6.0f * (k1 + k2 + k4);

    // y-tap clamped offsets + masks (z-independent)
    const int dys[6] = {-4, -2, -1, 1, 2, 4};
    int yoff[6]; float ym[6];
#pragma unroll
    for (int k = 0; k < 6; ++k) {
        const int yy = y + dys[k];
        const bool v = (unsigned)yy < 64u;
        yoff[k] = (v ? yy : y) * 64 + w0;
        ym[k]   = v ? 1.0f : 0.0f;
    }
    // w-tap clamped offsets + masks (quad-aligned)
    const bool wmv = (w0 >= 4), wpv = (w0 <= 56);
    const int   wmoff = wmv ? foff - 4 : foff;
    const int   wpoff = wpv ? foff + 4 : foff;
    const float wmm = wmv ? 1.0f : 0.0f, wpm = wpv ? 1.0f : 0.0f;

    // prologue: planes z0-4 .. z0+4 into slots q%10
#pragma unroll
    for (int i = 0; i < 9; ++i) {
        const int q = z0 - 4 + i;
        if (q >= 0 && q < 64)                 // uniform
            GLD(vol + (size_t)q * PLANE + foff, &lds[q % NSLOT][wbase]);
    }
    __syncthreads();

    const float4 zero = make_float4(0.f, 0.f, 0.f, 0.f);

    // named ring init: a_k = plane z0-4+k (k=0..7), from LDS
#define INITA(K) ((z0 - 4 + (K) >= 0)                                          \
    ? *(const float4*)(&lds[(z0 - 4 + (K)) % NSLOT][foff]) : zero)
    float4 a0 = INITA(0), a1 = INITA(1), a2 = INITA(2), a3 = INITA(3),
           a4 = INITA(4), a5 = INITA(5), a6 = INITA(6), a7 = INITA(7);
#undef INITA

    // incremental slot counters & pointers
    int slc = z0 % NSLOT;                     // slot of plane z
    int slf = (z0 + 4) % NSLOT;               // slot of plane z+4 (fill/tap)
    int slp = (z0 + 5) % NSLOT;               // slot of plane z+5 (prefetch)
    const float* gp  = vol  + (size_t)(z0 + 5) * PLANE + foff;
    float*       op_ = ovol + (size_t)z0 * PLANE + foff;

#pragma unroll 1
    for (int ib = 0; ib < CHUNK; ib += 8) {
        STEP(ib + 0, a0, a1, a2, a3, a4, a5, a6, a7)
        STEP(ib + 1, a1, a2, a3, a4, a5, a6, a7, a0)
        STEP(ib + 2, a2, a3, a4, a5, a6, a7, a0, a1)
        STEP(ib + 3, a3, a4, a5, a6, a7, a0, a1, a2)
        STEP(ib + 4, a4, a5, a6, a7, a0, a1, a2, a3)
        STEP(ib + 5, a5, a6, a7, a0, a1, a2, a3, a4)
        STEP(ib + 6, a6, a7, a0, a1, a2, a3, a4, a5)
        STEP(ib + 7, a7, a0, a1, a2, a3, a4, a5, a6)
    }
}

extern "C" void kernel_launch(void* const* d_in, const int* in_sizes, int n_in,
                              void* d_out, int out_size, void* d_ws, size_t ws_size,
                              hipStream_t stream) {
    const float* x = (const float*)d_in[0];
    const float* p = (const float*)d_in[1];
    float* out = (float*)d_out;
    lap3d_nring<<<256, 1024, 0, stream>>>(x, p, out);
}